// Round 5
// baseline (436.005 us; speedup 1.0000x reference)
//
#include <hip/hip_runtime.h>
#include <hip/hip_bf16.h>
#include <math.h>
#include <stdint.h>

#define B_     32
#define HH_    28
#define WW_    28
#define N_     784
#define C_     384
#define M_     25088      // B_*N_
#define HEADS_ 8
#define HD_    48
#define HID_   1536

typedef __bf16 bf16;
typedef __attribute__((ext_vector_type(8))) __bf16 bf16x8;
typedef __attribute__((ext_vector_type(4))) __bf16 bf16x4;
typedef __attribute__((ext_vector_type(4))) float f32x4;

// async global->LDS, 16B per lane; LDS dest = wave-uniform base + lane*16
__device__ __forceinline__ void gload_lds16(const void* g, void* l) {
    __builtin_amdgcn_global_load_lds(
        (const __attribute__((address_space(1))) unsigned int*)g,
        (__attribute__((address_space(3))) unsigned int*)(uintptr_t)l,
        16, 0, 0);
}

// fast exact-enough GELU: v*sigmoid(2u) == 0.5v(1+tanh(u)), u = 0.79788456(v+0.044715v^3)
__device__ __forceinline__ float gelu_f(float v) {
    float u = 0.7978845608028654f * v * (1.f + 0.044715f * v * v);
    return __fdividef(v, 1.f + __expf(-2.f * u));
}

// ---------------- weights fp32 -> bf16, all four in one launch ----------------
__global__ void convert4_kernel(const float* __restrict__ a, int na,
                                const float* __restrict__ b, int nb,
                                const float* __restrict__ c, int nc,
                                const float* __restrict__ d, int nd,
                                bf16* __restrict__ out) {
    int i = blockIdx.x * 256 + threadIdx.x;
    int j = i;
    const float* src;
    if (j < na) src = a + j;
    else { j -= na;
        if (j < nb) src = b + j;
        else { j -= nb;
            if (j < nc) src = c + j;
            else { j -= nc;
                if (j >= nd) return;
                src = d + j; } } }
    out[i] = (bf16)(*src);
}

// ---------------- CPE weight transpose: w[c][tap] -> wt[tap][c], both convs ---------
__global__ void wtrans_kernel(const float* __restrict__ w0, const float* __restrict__ w1,
                              float* __restrict__ wt0, float* __restrict__ wt1) {
    int i = blockIdx.x * 256 + threadIdx.x;     // 0..3455
    if (i >= C_ * 9) return;
    int c = i / 9, t = i - c * 9;
    wt0[t * C_ + c] = w0[i];
    wt1[t * C_ + c] = w1[i];
}

// ------- depthwise 3x3 conv + bias + residual, fused LayerNorm -> bf16 -------
__global__ __launch_bounds__(256)
void cpe_ln_kernel(const float* __restrict__ x, const float* __restrict__ wt,
                   const float* __restrict__ bias, float* __restrict__ y,
                   const float* __restrict__ g, const float* __restrict__ beta,
                   bf16* __restrict__ lnout) {
    const int wave = threadIdx.x >> 6, lane = threadIdx.x & 63;
    const int f = blockIdx.x;
    const int row = (f & 7) * 3136 + (f >> 3) * 4 + wave;   // bijective over M_
    const int b = row / N_;
    const int n = row - b * N_;
    const int py = n / WW_, px = n - py * WW_;

    float acc[6], ctr[6];
    const float* xrow = x + (size_t)row * C_ + lane;
    #pragma unroll
    for (int j = 0; j < 6; j++) {
        acc[j] = bias[lane + j * 64];
        ctr[j] = xrow[j * 64];
    }

    if (py >= 1 && py <= 26 && px >= 1 && px <= 26) {
        const float* p = x + (size_t)(row - WW_ - 1) * C_ + lane;
        float v[9][6];
        #pragma unroll
        for (int t = 0; t < 9; t++) {
            if (t == 4) continue;
            const float* pt = p + ((t / 3) * WW_ + (t % 3)) * C_;
            #pragma unroll
            for (int j = 0; j < 6; j++) v[t][j] = pt[j * 64];
        }
        #pragma unroll
        for (int t = 0; t < 9; t++) {
            #pragma unroll
            for (int j = 0; j < 6; j++) {
                float xv = (t == 4) ? ctr[j] : v[t][j];
                acc[j] += wt[t * C_ + lane + j * 64] * xv;
            }
        }
    } else {
        #pragma unroll
        for (int t = 0; t < 9; t++) {
            int yy = py + t / 3 - 1, xx = px + t % 3 - 1;
            if (yy < 0 || yy >= HH_ || xx < 0 || xx >= WW_) continue;
            const float* pt = x + (size_t)(b * N_ + yy * WW_ + xx) * C_ + lane;
            #pragma unroll
            for (int j = 0; j < 6; j++)
                acc[j] += wt[t * C_ + lane + j * 64] * pt[j * 64];
        }
    }
    #pragma unroll
    for (int j = 0; j < 6; j++) acc[j] += ctr[j];

    float* yrow = y + (size_t)row * C_ + lane;
    #pragma unroll
    for (int j = 0; j < 6; j++) yrow[j * 64] = acc[j];

    // ---- LN: wave-wide butterfly, no barriers ----
    float s = 0.f;
    #pragma unroll
    for (int j = 0; j < 6; j++) s += acc[j];
    #pragma unroll
    for (int off = 1; off < 64; off <<= 1) s += __shfl_xor(s, off, 64);
    float mean = s * (1.f / C_);
    float d[6], vs = 0.f;
    #pragma unroll
    for (int j = 0; j < 6; j++) { d[j] = acc[j] - mean; vs += d[j] * d[j]; }
    #pragma unroll
    for (int off = 1; off < 64; off <<= 1) vs += __shfl_xor(vs, off, 64);
    float rstd = rsqrtf(vs * (1.f / C_) + 1e-5f);
    bf16* lrow = lnout + (size_t)row * C_ + lane;
    #pragma unroll
    for (int j = 0; j < 6; j++) {
        int c = lane + j * 64;
        lrow[j * 64] = (bf16)(d[j] * rstd * g[c] + beta[c]);
    }
}

// ======== bf16 MFMA GEMM: phase-split schedule (T3+T4+T5), BM256xBN128xBK64 ========
// R12: the 2-barrier skeleton pinned at 17% MfmaUtil across 5 tilings (R7-R11) ->
// port the m201-style schedule:
//   * ring-3 K-tile buffers (48KB each, 144KB LDS, 1 block/CU), prefetch dist 2
//   * per K-tile: 2 phases, each {8 ds_read; issue 3 gloads(t+2); s_barrier;
//     lgkmcnt(0); setprio(1); 16 MFMA; setprio(0); s_barrier}
//   * counted vmcnt(6) folded into the tile-closing barrier -- NEVER 0 in-loop
//     (vmcnt retires in order, m135: <=6 outstanding => tile t+1 fully landed)
//   * race-safety: barriers keep waves in the same segment; tile t-1 reads finish
//     before its closing barrier (lgkmcnt precedes MFMA), so stage(t+2) into
//     buffer (t-1)%3 cannot race.
// LDS layout per tile: A = [khalf][256 rows][64B], B = [khalf][128 rows][64B]
// (R7's proven 64B-row + XOR-swizzle: slot4 ^= (row>>1)&3, 0 conflicts measured),
// inverse swizzle applied on the per-lane GLOBAL source (G21 both-sides form).
// 8 waves = 4m x 2n grid of the proven 64x64 wave job (acc[4][4], swapped-operand
// C^T fragments -> f32x4/bf16x4 vector epilogue, i-outer/j-inner for write combine).
template<bool BIAS, bool GELU, bool RESID, bool OUTBF>
__global__ __launch_bounds__(512, 2)
void gemm_kernel(const bf16* __restrict__ A, const bf16* __restrict__ Wt,
                 const float* __restrict__ bias, const float* __restrict__ resid,
                 void* __restrict__ outp, int M, int N, int K) {
    // per tile: A 16384 elem (32KB) + B 8192 elem (16KB) = 24576 elem; ring-3
    __shared__ __align__(16) bf16 S[3 * 24576];   // 144 KB

    const int nbn = gridDim.x, nbm = gridDim.y;
    const int f = blockIdx.y * nbn + blockIdx.x;
    const int grp = f / (8 * nbn);
    const int rem = f - grp * 8 * nbn;
    const int rows = min(8, nbm - grp * 8);
    const int bm = (grp * 8 + rem % rows) * 256;
    const int bn = (rem / rows) * 128;

    const int t = threadIdx.x;
    const int wave = t >> 6, lane = t & 63;
    const int wm = (wave >> 1) * 64;         // 4 m-rows of waves (256)
    const int wn = (wave & 1) * 64;          // 2 n-cols of waves (128)
    const int quad = lane >> 4, r = lane & 15;

    // ---- staging: 6 gload_lds16 per thread per K-tile ----
    // per-thread swizzled source column (elements): ((t&3) ^ ((t>>3)&3)) * 8
    const int colsw = ((t & 3) ^ ((t >> 3) & 3)) * 8;
    const int rA = t >> 2;                                  // 0..127
    const bf16* sA0 = A  + (size_t)(bm + rA)       * K + colsw;   // A rows 0-127
    const bf16* sA1 = A  + (size_t)(bm + 128 + rA) * K + colsw;   // A rows 128-255
    const bf16* sB  = Wt + (size_t)(bn + rA)       * K + colsw;   // B rows 0-127
    const int t8 = t * 8;                                   // LDS element offset

    const int nt = K >> 6;                                  // K-tiles of 64

    auto issue3 = [&](int tl, int ph) {
        bf16* buf = &S[(tl % 3) * 24576];
        const size_t ko = (size_t)tl * 64;
        if (ph == 0) {          // k-half 0
            gload_lds16(sA0 + ko, buf + 0 * 4096 + t8);     // A h0 rows 0-127
            gload_lds16(sA1 + ko, buf + 1 * 4096 + t8);     // A h0 rows 128-255
            gload_lds16(sB  + ko, buf + 4 * 4096 + t8);     // B h0
        } else {                // k-half 1
            gload_lds16(sA0 + ko + 32, buf + 2 * 4096 + t8);
            gload_lds16(sA1 + ko + 32, buf + 3 * 4096 + t8);
            gload_lds16(sB  + ko + 32, buf + 5 * 4096 + t8);
        }
    };

    f32x4 acc[4][4] = {};

    // prologue: tiles 0 and 1 in flight; wait tile 0 (leave tile 1's 6 outstanding)
    issue3(0, 0); issue3(0, 1); issue3(1, 0); issue3(1, 1);
    asm volatile("s_waitcnt vmcnt(6)" ::: "memory");
    __builtin_amdgcn_s_barrier();

    // read-side swizzle: slot4 = quad ^ ((r>>1)&3) (row&2,4 bits == r's)
    const int sq16 = (quad ^ ((r >> 1) & 3)) * 16;          // byte offset in 64B row

    for (int tl = 0; tl < nt; ++tl) {
        const char* as = (const char*)&S[(tl % 3) * 24576];
        const char* bs = as + 32768;                         // B region (bytes)
        #pragma unroll
        for (int s2 = 0; s2 < 2; ++s2) {
            bf16x8 af[4], bfr[4];
            #pragma unroll
            for (int i = 0; i < 4; i++)
                af[i] = *(const bf16x8*)(as + s2 * 16384 + (wm + i * 16 + r) * 64 + sq16);
            #pragma unroll
            for (int j = 0; j < 4; j++)
                bfr[j] = *(const bf16x8*)(bs + s2 * 8192 + (wn + j * 16 + r) * 64 + sq16);
            if (tl + 2 < nt) issue3(tl + 2, s2);
            __builtin_amdgcn_s_barrier();
            asm volatile("s_waitcnt lgkmcnt(0)" ::: "memory");
            __builtin_amdgcn_s_setprio(1);
            #pragma unroll
            for (int i = 0; i < 4; i++)
                #pragma unroll
                for (int j = 0; j < 4; j++)
                    // swapped operands: acc holds C^T fragment:
                    // n = bn+wn+j*16+quad*4+e (consecutive over e), m = bm+wm+i*16+r
                    acc[i][j] = __builtin_amdgcn_mfma_f32_16x16x32_bf16(bfr[j], af[i], acc[i][j], 0, 0, 0);
            __builtin_amdgcn_s_setprio(0);
            if (s2 == 1) {      // tile-closing: ensure tile tl+1 landed everywhere
                if (tl + 2 < nt)      asm volatile("s_waitcnt vmcnt(6)" ::: "memory");
                else if (tl + 1 < nt) asm volatile("s_waitcnt vmcnt(0)" ::: "memory");
            }
            __builtin_amdgcn_s_barrier();
        }
    }

    // ---- epilogue: i outer, j inner (4 adjacent 32B chunks/row back-to-back) ----
    #pragma unroll
    for (int i = 0; i < 4; i++) {
        const size_t m = (size_t)(bm + wm + i * 16 + r);
        #pragma unroll
        for (int j = 0; j < 4; j++) {
            const int n = bn + wn + j * 16 + quad * 4;
            f32x4 v = acc[i][j];
            if (BIAS) v += *(const f32x4*)(&bias[n]);
            if (GELU) {
                #pragma unroll
                for (int e = 0; e < 4; e++) v[e] = gelu_f(v[e]);
            }
            if (RESID) v += *(const f32x4*)(&resid[m * N + n]);
            if (OUTBF) {
                bf16x4 ov;
                #pragma unroll
                for (int e = 0; e < 4; e++) ov[e] = (bf16)v[e];
                *(bf16x4*)((bf16*)outp + m * N + n) = ov;
            } else {
                *(f32x4*)((float*)outp + m * N + n) = v;
            }
        }
    }
}

// ---------------- fused channel attention (scores + softmax + apply), MFMA ----------
__global__ __launch_bounds__(256)
void attn_fused_kernel(const bf16* __restrict__ qkvb, bf16* __restrict__ outp) {
    __shared__ __align__(16) bf16 stage[4][3872];
    __shared__ float Sred[4][48][49];
    __shared__ __align__(16) bf16 attn_s[48 * 72];

    const int bh = blockIdx.x;
    const int b = bh >> 3, h = bh & 7;
    const int t = threadIdx.x;
    const int wave = t >> 6, lane = t & 63;
    const int quad = lane >> 4, r = lane & 15;
    const int tensor = lane >> 5;
    const int n_local = lane & 31;

    const size_t qkv_base = (size_t)b * N_ * 1152;
    const int toff = 384 + tensor * 384 + h * 48;

    f32x4 acc[3][3] = {};
    bf16* kT = &stage[wave][0];
    bf16* vT = &stage[wave][1936];
    bf16* myT = &stage[wave][tensor * 1936];

    for (int c = wave; c < 25; c += 4) {
        int n0 = c * 32;
        bf16 rowbuf[48];
        if (n0 + n_local < N_) {
            const uint4* src = (const uint4*)(qkvb + qkv_base + (size_t)(n0 + n_local) * 1152 + toff);
            #pragma unroll
            for (int i = 0; i < 6; i++) *(uint4*)(&rowbuf[i * 8]) = src[i];
        } else {
            #pragma unroll
            for (int i = 0; i < 48; i++) rowbuf[i] = (bf16)0.f;
        }
        #pragma unroll
        for (int d = 0; d < 48; d++) myT[d * 40 + n_local] = rowbuf[d];
        bf16x8 af[3], bfv[3];
        #pragma unroll
        for (int i = 0; i < 3; i++) af[i]  = *(const bf16x8*)(&kT[(i * 16 + r) * 40 + quad * 8]);
        #pragma unroll
        for (int j = 0; j < 3; j++) bfv[j] = *(const bf16x8*)(&vT[(j * 16 + r) * 40 + quad * 8]);
        #pragma unroll
        for (int i = 0; i < 3; i++)
            #pragma unroll
            for (int j = 0; j < 3; j++)
                acc[i][j] = __builtin_amdgcn_mfma_f32_16x16x32_bf16(af[i], bfv[j], acc[i][j], 0, 0, 0);
    }

    #pragma unroll
    for (int i = 0; i < 3; i++)
        #pragma unroll
        for (int j = 0; j < 3; j++)
            #pragma unroll
            for (int e = 0; e < 4; e++)
                Sred[wave][i * 16 + quad * 4 + e][j * 16 + r] = acc[i][j][e];
    __syncthreads();

    if (t < 48) {
        float row[48];
        float mx = -1e30f;
        #pragma unroll
        for (int e = 0; e < 48; e++) {
            float s = Sred[0][t][e] + Sred[1][t][e] + Sred[2][t][e] + Sred[3][t][e];
            s *= 0.14433756729740644f;
            row[e] = s;
            mx = fmaxf(mx, s);
        }
        float sum = 0.f;
        #pragma unroll
        for (int e = 0; e < 48; e++) { float ex = __expf(row[e] - mx); row[e] = ex; sum += ex; }
        float inv = 1.f / sum;
        #pragma unroll
        for (int e = 0; e < 48; e++) attn_s[t * 72 + e] = (bf16)(row[e] * inv);
        #pragma unroll
        for (int e = 48; e < 64; e++) attn_s[t * 72 + e] = (bf16)0.f;
    }
    __syncthreads();

    const bf16* qbase = qkvb + qkv_base + h * 48;
    for (int nt = wave; nt < 49; nt += 4) {
        int n0 = nt * 16;
        f32x4 oacc[3] = {};
        #pragma unroll
        for (int kc = 0; kc < 2; kc++) {
            bf16x8 bq = *(const bf16x8*)(qbase + (size_t)(n0 + r) * 1152 + kc * 32 + quad * 8);
            #pragma unroll
            for (int i = 0; i < 3; i++) {
                bf16x8 aa = *(const bf16x8*)(&attn_s[(i * 16 + r) * 72 + kc * 32 + quad * 8]);
                oacc[i] = __builtin_amdgcn_mfma_f32_16x16x32_bf16(aa, bq, oacc[i], 0, 0, 0);
            }
        }
        #pragma unroll
        for (int i = 0; i < 3; i++) {
            bf16x4 ov;
            #pragma unroll
            for (int e = 0; e < 4; e++) ov[e] = (bf16)oacc[i][e];
            *(bf16x4*)(outp + (size_t)(b * N_ + n0 + r) * 384 + h * 48 + i * 16 + quad * 4) = ov;
        }
    }
}

// ---------------- launch ----------------
extern "C" void kernel_launch(void* const* d_in, const int* in_sizes, int n_in,
                              void* d_out, int out_size, void* d_ws, size_t ws_size,
                              hipStream_t stream) {
    const float* x      = (const float*)d_in[0];
    const float* cpe0_w = (const float*)d_in[3];
    const float* cpe0_b = (const float*)d_in[4];
    const float* cpe1_w = (const float*)d_in[5];
    const float* cpe1_b = (const float*)d_in[6];
    const float* n1g    = (const float*)d_in[7];
    const float* n1b    = (const float*)d_in[8];
    const float* qkv_w  = (const float*)d_in[9];
    const float* proj_w = (const float*)d_in[10];
    const float* proj_b = (const float*)d_in[11];
    const float* n2g    = (const float*)d_in[12];
    const float* n2b    = (const float*)d_in[13];
    const float* fc1_w  = (const float*)d_in[14];
    const float* fc1_b  = (const float*)d_in[15];
    const float* fc2_w  = (const float*)d_in[16];
    const float* fc2_b  = (const float*)d_in[17];

    char* ws = (char*)d_ws;
    size_t off = 0;
    bf16* cur    = (bf16*)(ws + off); off += (size_t)M_ * C_ * 2;
    bf16* qkvb   = (bf16*)(ws + off);
    float* x3    = (float*)qkvb;
    off += (size_t)M_ * 1152 * 2;
    bf16* hbuf   = (bf16*)(ws + off); off += (size_t)M_ * HID_ * 2;
    bf16* qkv_wb  = (bf16*)(ws + off); off += (size_t)1152 * 384 * 2;
    bf16* proj_wb = (bf16*)(ws + off); off += (size_t)384 * 384 * 2;
    bf16* fc1_wb  = (bf16*)(ws + off); off += (size_t)HID_ * 384 * 2;
    bf16* fc2_wb  = (bf16*)(ws + off); off += (size_t)384 * HID_ * 2;
    float* wt0    = (float*)(ws + off); off += (size_t)C_ * 9 * 4;
    float* wt1    = (float*)(ws + off); off += (size_t)C_ * 9 * 4;
    float* out = (float*)d_out;   // doubles as x1/x2 trunk buffer

    const int na = 442368, nb = 147456, nc = 589824, nd = 589824;
    convert4_kernel<<<(na + nb + nc + nd + 255) / 256, 256, 0, stream>>>(
        qkv_w, na, proj_w, nb, fc1_w, nc, fc2_w, nd, qkv_wb);
    wtrans_kernel<<<(C_ * 9 + 255) / 256, 256, 0, stream>>>(cpe0_w, cpe1_w, wt0, wt1);

    // CPE0 + LN1: x -> out (x1, fp32) and cur (bf16)
    cpe_ln_kernel<<<M_ / 4, 256, 0, stream>>>(x, wt0, cpe0_b, out, n1g, n1b, cur);
    // qkv: cur @ qkv_w^T -> qkvb  (M x 1152, K=384)
    gemm_kernel<false, false, false, true><<<dim3(1152 / 128, M_ / 256), 512, 0, stream>>>(
        cur, qkv_wb, nullptr, nullptr, qkvb, M_, 1152, 384);
    // fused channel attention -> cur
    attn_fused_kernel<<<256, 256, 0, stream>>>(qkvb, cur);
    // proj + bias + residual -> out (fp32)
    gemm_kernel<true, false, true, false><<<dim3(384 / 128, M_ / 256), 512, 0, stream>>>(
        cur, proj_wb, proj_b, out, out, M_, 384, 384);
    // CPE1 + LN2: out (x2) -> x3 (fp32) and cur (bf16)
    cpe_ln_kernel<<<M_ / 4, 256, 0, stream>>>(out, wt1, cpe1_b, x3, n2g, n2b, cur);
    // fc1 + bias + gelu -> hbuf (bf16), M x 1536, K=384
    gemm_kernel<true, true, false, true><<<dim3(HID_ / 128, M_ / 256), 512, 0, stream>>>(
        cur, fc1_wb, fc1_b, nullptr, hbuf, M_, HID_, 384);
    // fc2 + bias + residual x3 -> d_out (fp32), M x 384, K=1536
    gemm_kernel<true, false, true, false><<<dim3(384 / 128, M_ / 256), 512, 0, stream>>>(
        hbuf, fc2_wb, fc2_b, x3, out, M_, 384, HID_);
}

// Round 6
// 372.980 us; speedup vs baseline: 1.1690x; 1.1690x over previous
//
#include <hip/hip_runtime.h>
#include <hip/hip_bf16.h>
#include <math.h>
#include <stdint.h>

#define B_     32
#define HH_    28
#define WW_    28
#define N_     784
#define C_     384
#define M_     25088      // B_*N_
#define HEADS_ 8
#define HD_    48
#define HID_   1536

typedef __bf16 bf16;
typedef __attribute__((ext_vector_type(8))) __bf16 bf16x8;
typedef __attribute__((ext_vector_type(4))) __bf16 bf16x4;
typedef __attribute__((ext_vector_type(4))) float f32x4;

// async global->LDS, 16B per lane; LDS dest = wave-uniform base + lane*16
__device__ __forceinline__ void gload_lds16(const void* g, void* l) {
    __builtin_amdgcn_global_load_lds(
        (const __attribute__((address_space(1))) unsigned int*)g,
        (__attribute__((address_space(3))) unsigned int*)(uintptr_t)l,
        16, 0, 0);
}

// fast GELU: v*sigmoid(2u), u = 0.79788456(v+0.044715v^3); validated R8-R12:
// absmax identical (0.03125) to erff baseline under bf16 rounding.
__device__ __forceinline__ float gelu_f(float v) {
    float u = 0.7978845608028654f * v * (1.f + 0.044715f * v * v);
    return __fdividef(v, 1.f + __expf(-2.f * u));
}

// ---------------- weights fp32 -> bf16, all four in one launch ----------------
__global__ void convert4_kernel(const float* __restrict__ a, int na,
                                const float* __restrict__ b, int nb,
                                const float* __restrict__ c, int nc,
                                const float* __restrict__ d, int nd,
                                bf16* __restrict__ out) {
    int i = blockIdx.x * 256 + threadIdx.x;
    int j = i;
    const float* src;
    if (j < na) src = a + j;
    else { j -= na;
        if (j < nb) src = b + j;
        else { j -= nb;
            if (j < nc) src = c + j;
            else { j -= nc;
                if (j >= nd) return;
                src = d + j; } } }
    out[i] = (bf16)(*src);
}

// ---------------- CPE weight transpose: w[c][tap] -> wt[tap][c], both convs ---------
__global__ void wtrans_kernel(const float* __restrict__ w0, const float* __restrict__ w1,
                              float* __restrict__ wt0, float* __restrict__ wt1) {
    int i = blockIdx.x * 256 + threadIdx.x;     // 0..3455
    if (i >= C_ * 9) return;
    int c = i / 9, t = i - c * 9;
    wt0[t * C_ + c] = w0[i];
    wt1[t * C_ + c] = w1[i];
}

// ------- depthwise 3x3 conv + bias + residual, fused LayerNorm -> bf16 -------
// ONE WAVE PER ROW: lane l owns channels {l, l+64, ..., l+320}. LN reduction is a
// pure __shfl_xor butterfly — zero barriers, zero LDS. Border branch is
// wave-uniform (py/px per-row). Interior: 48 independent coalesced dword loads
// in flight. XCD-chunk swizzle: block f -> rows (f%8)*3136 + (f>>3)*4, so each
// XCD works on 4 whole images -> vertical 3x3 re-reads hit its own L2.
__global__ __launch_bounds__(256)
void cpe_ln_kernel(const float* __restrict__ x, const float* __restrict__ wt,
                   const float* __restrict__ bias, float* __restrict__ y,
                   const float* __restrict__ g, const float* __restrict__ beta,
                   bf16* __restrict__ lnout) {
    const int wave = threadIdx.x >> 6, lane = threadIdx.x & 63;
    const int f = blockIdx.x;
    const int row = (f & 7) * 3136 + (f >> 3) * 4 + wave;   // bijective over M_
    const int b = row / N_;
    const int n = row - b * N_;
    const int py = n / WW_, px = n - py * WW_;

    float acc[6], ctr[6];
    const float* xrow = x + (size_t)row * C_ + lane;
    #pragma unroll
    for (int j = 0; j < 6; j++) {
        acc[j] = bias[lane + j * 64];
        ctr[j] = xrow[j * 64];
    }

    if (py >= 1 && py <= 26 && px >= 1 && px <= 26) {
        // interior: 8 taps loaded unconditionally (center reuses ctr)
        const float* p = x + (size_t)(row - WW_ - 1) * C_ + lane;
        float v[9][6];
        #pragma unroll
        for (int t = 0; t < 9; t++) {
            if (t == 4) continue;
            const float* pt = p + ((t / 3) * WW_ + (t % 3)) * C_;
            #pragma unroll
            for (int j = 0; j < 6; j++) v[t][j] = pt[j * 64];
        }
        #pragma unroll
        for (int t = 0; t < 9; t++) {
            #pragma unroll
            for (int j = 0; j < 6; j++) {
                float xv = (t == 4) ? ctr[j] : v[t][j];
                acc[j] += wt[t * C_ + lane + j * 64] * xv;
            }
        }
    } else {
        #pragma unroll
        for (int t = 0; t < 9; t++) {
            int yy = py + t / 3 - 1, xx = px + t % 3 - 1;
            if (yy < 0 || yy >= HH_ || xx < 0 || xx >= WW_) continue;
            const float* pt = x + (size_t)(b * N_ + yy * WW_ + xx) * C_ + lane;
            #pragma unroll
            for (int j = 0; j < 6; j++)
                acc[j] += wt[t * C_ + lane + j * 64] * pt[j * 64];
        }
    }
    #pragma unroll
    for (int j = 0; j < 6; j++) acc[j] += ctr[j];

    float* yrow = y + (size_t)row * C_ + lane;
    #pragma unroll
    for (int j = 0; j < 6; j++) yrow[j * 64] = acc[j];

    // ---- LN: wave-wide butterfly, no barriers ----
    float s = 0.f;
    #pragma unroll
    for (int j = 0; j < 6; j++) s += acc[j];
    #pragma unroll
    for (int off = 1; off < 64; off <<= 1) s += __shfl_xor(s, off, 64);
    float mean = s * (1.f / C_);
    float d[6], vs = 0.f;
    #pragma unroll
    for (int j = 0; j < 6; j++) { d[j] = acc[j] - mean; vs += d[j] * d[j]; }
    #pragma unroll
    for (int off = 1; off < 64; off <<= 1) vs += __shfl_xor(vs, off, 64);
    float rstd = rsqrtf(vs * (1.f / C_) + 1e-5f);
    bf16* lrow = lnout + (size_t)row * C_ + lane;
    #pragma unroll
    for (int j = 0; j < 6; j++) {
        int c = lane + j * 64;
        lrow[j * 64] = (bf16)(d[j] * rstd * g[c] + beta[c]);
    }
}

// -------- bf16 MFMA GEMM: R0-exact 3-stage ring (verified 375.6us total) --------
// R13: after R8-R12 all regressed on total, this is the R0 kernel byte-for-byte
// EXCEPT two zero-cost, four-rounds-validated deltas:
//   * erff -> gelu_f (fc1 VALU tax; absmax unchanged at 0.03125 across R8-R12)
//   * LDS XOR-swizzle pair (inverse-swizzled gload SOURCE + XOR'd read):
//     conflicts 3.6M -> 0 at zero VGPR/instruction cost (proven R8-R12).
// Evidence R0-R12: fc1 = 29.6GF at 65-68us ≈ 455TF across six structures ->
// skinny-K (384) structural ceiling of the 2-barrier family; tile/ring/phase
// knobs are drain-hidden. Do not restructure further.
template<bool BIAS, bool GELU, bool RESID, bool OUTBF>
__global__ __launch_bounds__(256)
void gemm_kernel(const bf16* __restrict__ A, const bf16* __restrict__ Wt,
                 const float* __restrict__ bias, const float* __restrict__ resid,
                 void* __restrict__ outp, int M, int N, int K) {
    __shared__ __align__(16) bf16 As[3 * 4096];
    __shared__ __align__(16) bf16 Bs[3 * 4096];

    const int nbn = gridDim.x, nbm = gridDim.y;
    const int f = blockIdx.y * nbn + blockIdx.x;
    const int grp = f / (8 * nbn);
    const int rem = f - grp * 8 * nbn;
    const int rows = min(8, nbm - grp * 8);
    const int bm = (grp * 8 + rem % rows) * 128;
    const int bn = (rem / rows) * 128;

    const int t = threadIdx.x;
    const int wave = t >> 6, lane = t & 63;
    const int wm = (wave & 1) * 64, wn = (wave >> 1) * 64;
    const int quad = lane >> 4, r = lane & 15;

    const int ldrow = lane >> 2;
    // inverse swizzle on the global source: col-slot ^= row[2:1] (row_local = lane>>2)
    const int ldcol = ((lane & 3) ^ ((lane >> 3) & 3)) * 8;
    const bf16* ga0 = A  + (size_t)(bm + wave * 32 + ldrow) * K + ldcol;
    const bf16* ga1 = ga0 + (size_t)16 * K;
    const bf16* gb0 = Wt + (size_t)(bn + wave * 32 + ldrow) * K + ldcol;
    const bf16* gb1 = gb0 + (size_t)16 * K;
    const int lbase = wave * 32 * 32;

    f32x4 acc[4][4] = {};

    gload_lds16(ga0, &As[lbase]);
    gload_lds16(ga1, &As[lbase + 512]);
    gload_lds16(gb0, &Bs[lbase]);
    gload_lds16(gb1, &Bs[lbase + 512]);
    gload_lds16(ga0 + 32, &As[4096 + lbase]);
    gload_lds16(ga1 + 32, &As[4096 + lbase + 512]);
    gload_lds16(gb0 + 32, &Bs[4096 + lbase]);
    gload_lds16(gb1 + 32, &Bs[4096 + lbase + 512]);

    // read-side swizzle: col-quad ^= r[2:1] (row bits beyond r are multiples of 16)
    const int sq = (quad ^ ((r >> 1) & 3)) * 8;

    int buf = 0;
    int k0 = 0;
    for (; k0 < K - 32; k0 += 32) {
        asm volatile("s_waitcnt vmcnt(4)" ::: "memory");
        asm volatile("s_barrier" ::: "memory");
        if (k0 + 64 < K) {
            const int nb3 = (buf == 0 ? 2 : buf - 1) * 4096;   // (buf+2)%3
            gload_lds16(ga0 + k0 + 64, &As[nb3 + lbase]);
            gload_lds16(ga1 + k0 + 64, &As[nb3 + lbase + 512]);
            gload_lds16(gb0 + k0 + 64, &Bs[nb3 + lbase]);
            gload_lds16(gb1 + k0 + 64, &Bs[nb3 + lbase + 512]);
        }
        const bf16* as = &As[buf * 4096];
        const bf16* bs = &Bs[buf * 4096];
        bf16x8 af[4], bfr[4];
        #pragma unroll
        for (int i = 0; i < 4; i++)
            af[i] = *(const bf16x8*)(&as[(wm + i * 16 + r) * 32 + sq]);
        #pragma unroll
        for (int j = 0; j < 4; j++)
            bfr[j] = *(const bf16x8*)(&bs[(wn + j * 16 + r) * 32 + sq]);
        #pragma unroll
        for (int i = 0; i < 4; i++)
            #pragma unroll
            for (int j = 0; j < 4; j++)
                acc[i][j] = __builtin_amdgcn_mfma_f32_16x16x32_bf16(af[i], bfr[j], acc[i][j], 0, 0, 0);
        buf = (buf == 2) ? 0 : buf + 1;
    }
    {
        asm volatile("s_waitcnt vmcnt(0)" ::: "memory");
        asm volatile("s_barrier" ::: "memory");
        const bf16* as = &As[buf * 4096];
        const bf16* bs = &Bs[buf * 4096];
        bf16x8 af[4], bfr[4];
        #pragma unroll
        for (int i = 0; i < 4; i++)
            af[i] = *(const bf16x8*)(&as[(wm + i * 16 + r) * 32 + sq]);
        #pragma unroll
        for (int j = 0; j < 4; j++)
            bfr[j] = *(const bf16x8*)(&bs[(wn + j * 16 + r) * 32 + sq]);
        #pragma unroll
        for (int i = 0; i < 4; i++)
            #pragma unroll
            for (int j = 0; j < 4; j++)
                acc[i][j] = __builtin_amdgcn_mfma_f32_16x16x32_bf16(af[i], bfr[j], acc[i][j], 0, 0, 0);
    }

    #pragma unroll
    for (int i = 0; i < 4; i++) {
        #pragma unroll
        for (int j = 0; j < 4; j++) {
            int n = bn + wn + j * 16 + r;
            float bv = BIAS ? bias[n] : 0.f;
            #pragma unroll
            for (int e = 0; e < 4; e++) {
                int m = bm + wm + i * 16 + quad * 4 + e;
                float val = acc[i][j][e] + bv;
                if (GELU) val = gelu_f(val);
                if (RESID) val += resid[(size_t)m * N + n];
                if (OUTBF) ((bf16*)outp)[(size_t)m * N + n] = (bf16)val;
                else       ((float*)outp)[(size_t)m * N + n] = val;
            }
        }
    }
}

// ---------------- fused channel attention (scores + softmax + apply), MFMA ----------
__global__ __launch_bounds__(256)
void attn_fused_kernel(const bf16* __restrict__ qkvb, bf16* __restrict__ outp) {
    __shared__ __align__(16) bf16 stage[4][3872];
    __shared__ float Sred[4][48][49];
    __shared__ __align__(16) bf16 attn_s[48 * 72];

    const int bh = blockIdx.x;
    const int b = bh >> 3, h = bh & 7;
    const int t = threadIdx.x;
    const int wave = t >> 6, lane = t & 63;
    const int quad = lane >> 4, r = lane & 15;
    const int tensor = lane >> 5;
    const int n_local = lane & 31;

    const size_t qkv_base = (size_t)b * N_ * 1152;
    const int toff = 384 + tensor * 384 + h * 48;

    f32x4 acc[3][3] = {};
    bf16* kT = &stage[wave][0];
    bf16* vT = &stage[wave][1936];
    bf16* myT = &stage[wave][tensor * 1936];

    for (int c = wave; c < 25; c += 4) {
        int n0 = c * 32;
        bf16 rowbuf[48];
        if (n0 + n_local < N_) {
            const uint4* src = (const uint4*)(qkvb + qkv_base + (size_t)(n0 + n_local) * 1152 + toff);
            #pragma unroll
            for (int i = 0; i < 6; i++) *(uint4*)(&rowbuf[i * 8]) = src[i];
        } else {
            #pragma unroll
            for (int i = 0; i < 48; i++) rowbuf[i] = (bf16)0.f;
        }
        #pragma unroll
        for (int d = 0; d < 48; d++) myT[d * 40 + n_local] = rowbuf[d];
        bf16x8 af[3], bfv[3];
        #pragma unroll
        for (int i = 0; i < 3; i++) af[i]  = *(const bf16x8*)(&kT[(i * 16 + r) * 40 + quad * 8]);
        #pragma unroll
        for (int j = 0; j < 3; j++) bfv[j] = *(const bf16x8*)(&vT[(j * 16 + r) * 40 + quad * 8]);
        #pragma unroll
        for (int i = 0; i < 3; i++)
            #pragma unroll
            for (int j = 0; j < 3; j++)
                acc[i][j] = __builtin_amdgcn_mfma_f32_16x16x32_bf16(af[i], bfv[j], acc[i][j], 0, 0, 0);
    }

    #pragma unroll
    for (int i = 0; i < 3; i++)
        #pragma unroll
        for (int j = 0; j < 3; j++)
            #pragma unroll
            for (int e = 0; e < 4; e++)
                Sred[wave][i * 16 + quad * 4 + e][j * 16 + r] = acc[i][j][e];
    __syncthreads();

    if (t < 48) {
        float row[48];
        float mx = -1e30f;
        #pragma unroll
        for (int e = 0; e < 48; e++) {
            float s = Sred[0][t][e] + Sred[1][t][e] + Sred[2][t][e] + Sred[3][t][e];
            s *= 0.14433756729740644f;
            row[e] = s;
            mx = fmaxf(mx, s);
        }
        float sum = 0.f;
        #pragma unroll
        for (int e = 0; e < 48; e++) { float ex = __expf(row[e] - mx); row[e] = ex; sum += ex; }
        float inv = 1.f / sum;
        #pragma unroll
        for (int e = 0; e < 48; e++) attn_s[t * 72 + e] = (bf16)(row[e] * inv);
        #pragma unroll
        for (int e = 48; e < 64; e++) attn_s[t * 72 + e] = (bf16)0.f;
    }
    __syncthreads();

    const bf16* qbase = qkvb + qkv_base + h * 48;
    for (int nt = wave; nt < 49; nt += 4) {
        int n0 = nt * 16;
        f32x4 oacc[3] = {};
        #pragma unroll
        for (int kc = 0; kc < 2; kc++) {
            bf16x8 bq = *(const bf16x8*)(qbase + (size_t)(n0 + r) * 1152 + kc * 32 + quad * 8);
            #pragma unroll
            for (int i = 0; i < 3; i++) {
                bf16x8 aa = *(const bf16x8*)(&attn_s[(i * 16 + r) * 72 + kc * 32 + quad * 8]);
                oacc[i] = __builtin_amdgcn_mfma_f32_16x16x32_bf16(aa, bq, oacc[i], 0, 0, 0);
            }
        }
        #pragma unroll
        for (int i = 0; i < 3; i++) {
            bf16x4 ov;
            #pragma unroll
            for (int e = 0; e < 4; e++) ov[e] = (bf16)oacc[i][e];
            *(bf16x4*)(outp + (size_t)(b * N_ + n0 + r) * 384 + h * 48 + i * 16 + quad * 4) = ov;
        }
    }
}

// ---------------- launch ----------------
extern "C" void kernel_launch(void* const* d_in, const int* in_sizes, int n_in,
                              void* d_out, int out_size, void* d_ws, size_t ws_size,
                              hipStream_t stream) {
    const float* x      = (const float*)d_in[0];
    const float* cpe0_w = (const float*)d_in[3];
    const float* cpe0_b = (const float*)d_in[4];
    const float* cpe1_w = (const float*)d_in[5];
    const float* cpe1_b = (const float*)d_in[6];
    const float* n1g    = (const float*)d_in[7];
    const float* n1b    = (const float*)d_in[8];
    const float* qkv_w  = (const float*)d_in[9];
    const float* proj_w = (const float*)d_in[10];
    const float* proj_b = (const float*)d_in[11];
    const float* n2g    = (const float*)d_in[12];
    const float* n2b    = (const float*)d_in[13];
    const float* fc1_w  = (const float*)d_in[14];
    const float* fc1_b  = (const float*)d_in[15];
    const float* fc2_w  = (const float*)d_in[16];
    const float* fc2_b  = (const float*)d_in[17];

    char* ws = (char*)d_ws;
    size_t off = 0;
    bf16* cur    = (bf16*)(ws + off); off += (size_t)M_ * C_ * 2;
    bf16* qkvb   = (bf16*)(ws + off);
    float* x3    = (float*)qkvb;
    off += (size_t)M_ * 1152 * 2;
    bf16* hbuf   = (bf16*)(ws + off); off += (size_t)M_ * HID_ * 2;
    bf16* qkv_wb  = (bf16*)(ws + off); off += (size_t)1152 * 384 * 2;
    bf16* proj_wb = (bf16*)(ws + off); off += (size_t)384 * 384 * 2;
    bf16* fc1_wb  = (bf16*)(ws + off); off += (size_t)HID_ * 384 * 2;
    bf16* fc2_wb  = (bf16*)(ws + off); off += (size_t)384 * HID_ * 2;
    float* wt0    = (float*)(ws + off); off += (size_t)C_ * 9 * 4;
    float* wt1    = (float*)(ws + off); off += (size_t)C_ * 9 * 4;
    float* out = (float*)d_out;   // doubles as x1/x2 trunk buffer

    const int na = 442368, nb = 147456, nc = 589824, nd = 589824;
    convert4_kernel<<<(na + nb + nc + nd + 255) / 256, 256, 0, stream>>>(
        qkv_w, na, proj_w, nb, fc1_w, nc, fc2_w, nd, qkv_wb);
    wtrans_kernel<<<(C_ * 9 + 255) / 256, 256, 0, stream>>>(cpe0_w, cpe1_w, wt0, wt1);

    // CPE0 + LN1: x -> out (x1, fp32) and cur (bf16)
    cpe_ln_kernel<<<M_ / 4, 256, 0, stream>>>(x, wt0, cpe0_b, out, n1g, n1b, cur);
    // qkv: cur @ qkv_w^T -> qkvb  (M x 1152, K=384)
    gemm_kernel<false, false, false, true><<<dim3(1152 / 128, M_ / 128), 256, 0, stream>>>(
        cur, qkv_wb, nullptr, nullptr, qkvb, M_, 1152, 384);
    // fused channel attention -> cur
    attn_fused_kernel<<<256, 256, 0, stream>>>(qkvb, cur);
    // proj + bias + residual -> out (fp32)
    gemm_kernel<true, false, true, false><<<dim3(384 / 128, M_ / 128), 256, 0, stream>>>(
        cur, proj_wb, proj_b, out, out, M_, 384, 384);
    // CPE1 + LN2: out (x2) -> x3 (fp32) and cur (bf16)
    cpe_ln_kernel<<<M_ / 4, 256, 0, stream>>>(out, wt1, cpe1_b, x3, n2g, n2b, cur);
    // fc1 + bias + gelu -> hbuf (bf16), M x 1536, K=384
    gemm_kernel<true, true, false, true><<<dim3(HID_ / 128, M_ / 128), 256, 0, stream>>>(
        cur, fc1_wb, fc1_b, nullptr, hbuf, M_, HID_, 384);
    // fc2 + bias + residual x3 -> d_out (fp32), M x 384, K=1536
    gemm_kernel<true, false, true, false><<<dim3(384 / 128, M_ / 128), 256, 0, stream>>>(
        hbuf, fc2_wb, fc2_b, x3, out, M_, 384, HID_);
}